// Round 7
// baseline (37.483 us; speedup 1.0000x reference)
//
#include <hip/hip_runtime.h>
#include <math.h>

// Problem constants (match reference setup_inputs)
#define KF   11
#define PAD  5          // KF/2
#define NB   4
#define CH   3
#define HH   256
#define WW   256
#define HWSZ (HH * WW)
#define EPS2 (1e-3f * 1e-3f)

#define RPB   4                    // output rows per block
#define SROWS (RPB + KF - 1)       // 14 staged rows per channel
#define LW    272                  // LDS row width (floats)
#define LPAD  8                    // left pad: quad-aligned windows cover the -5 halo
#define LW4   (LW / 4)             // 68 float4 per LDS row
#define STOT  (CH * SROWS * LW4)   // 2856 float4 staging elements

#define GRID      (NB * (HH / RPB))   // 256 blocks
#define FXSCALE_D 1048576.0           // 2^20 fixed-point scale (double)

// Fused: reconstruction + Charbonnier + grid reduction, NO second kernel.
// Per-block sums -> one RELAXED fixed-point u64 atomicAdd (bit-exact,
// order-independent, no cache-invalidating fences — round 5's acq_rel
// regression came from 512 buffer_inv/wbl2 ops). Ordering of fx-add before
// counter-add is enforced per-wave by a data dependency on the returned
// old value (forces s_waitcnt vmcnt(0) — wave-local, no cache ops).
// ws: [0..7] u64 total, [8..11] u32 counter (zeroed by hipMemsetAsync).
__global__ __launch_bounds__(256) void recon_charbonnier_fused(
    const float* __restrict__ image1,
    const float* __restrict__ image2,
    const float* __restrict__ filters,
    unsigned long long* __restrict__ total_fx,
    unsigned int* __restrict__ counter,
    float* __restrict__ out)
{
    __shared__ float limg[CH][SROWS][LW];   // 45,696 B
    __shared__ float wsum[4];

    const int tid = threadIdx.x;
    const int p   = tid & 63;
    const int r   = tid >> 6;          // 0..3: output row within band
    const int b   = blockIdx.x;
    const int n   = b >> 6;            // 4 batches
    const int h0  = (b & 63) << 2;     // 64 bands of 4 rows

    const float* __restrict__ img1n = image1 + (size_t)n * CH * HWSZ;

    // ---- stage image1 band (rows h0-5 .. h0+8, 3 ch) into LDS, zero halo ----
    for (int idx = tid; idx < STOT; idx += 256) {
        const int row = idx / LW4;            // ch*SROWS + rr
        const int c4  = idx - row * LW4;      // 0..67
        const int ch  = row / SROWS;
        const int rr  = row - ch * SROWS;
        const int grow = h0 + rr - PAD;
        const int gcol = (c4 << 2) - LPAD;
        float4 v = make_float4(0.f, 0.f, 0.f, 0.f);
        if ((unsigned)grow < (unsigned)HH && (unsigned)gcol <= (unsigned)(WW - 4))
            v = *(const float4*)(img1n + (size_t)ch * HWSZ
                                       + (size_t)grow * WW + gcol);
        *(float4*)&limg[ch][rr][c4 << 2] = v;
    }
    __syncthreads();

    // ---- tap loop: all 11 dh rows per thread, quad-aligned LDS windows ----
    const int w0 = p << 2;
    const float* __restrict__ fp = filters + (size_t)n * (KF * KF) * HWSZ
                                           + (size_t)(h0 + r) * WW + w0;

    float acc[CH][4] = {};

    for (int dh = 0; dh < KF; ++dh) {
        float4 fv[KF];
        #pragma unroll
        for (int dw = 0; dw < KF; ++dw)
            fv[dw] = *(const float4*)(fp + (size_t)(dh * KF + dw) * HWSZ);

        #pragma unroll
        for (int ch = 0; ch < CH; ++ch) {
            // quad-aligned window: win[k] = limg[ch][r+dh][w0 + k], k=0..19
            float win[20];
            #pragma unroll
            for (int k = 0; k < 5; ++k) {
                const float4 q = *(const float4*)&limg[ch][r + dh][w0 + (k << 2)];
                win[4 * k + 0] = q.x;
                win[4 * k + 1] = q.y;
                win[4 * k + 2] = q.z;
                win[4 * k + 3] = q.w;
            }
            // output px w0+j needs global col (w0+j)+dw-5 -> win[dw+j+3]
            #pragma unroll
            for (int dw = 0; dw < KF; ++dw) {
                acc[ch][0] = fmaf(fv[dw].x, win[dw + 3], acc[ch][0]);
                acc[ch][1] = fmaf(fv[dw].y, win[dw + 4], acc[ch][1]);
                acc[ch][2] = fmaf(fv[dw].z, win[dw + 5], acc[ch][2]);
                acc[ch][3] = fmaf(fv[dw].w, win[dw + 6], acc[ch][3]);
            }
        }
    }

    // ---- Charbonnier over 3 ch x 4 px ----
    const float* __restrict__ img2p = image2 + (size_t)n * CH * HWSZ
                                             + (size_t)(h0 + r) * WW + w0;
    float s = 0.f;
    #pragma unroll
    for (int ch = 0; ch < CH; ++ch) {
        const float4 t2 = *(const float4*)(img2p + (size_t)ch * HWSZ);
        const float d0 = acc[ch][0] - t2.x;
        const float d1 = acc[ch][1] - t2.y;
        const float d2 = acc[ch][2] - t2.z;
        const float d3 = acc[ch][3] - t2.w;
        s += sqrtf(d0 * d0 + EPS2) + sqrtf(d1 * d1 + EPS2)
           + sqrtf(d2 * d2 + EPS2) + sqrtf(d3 * d3 + EPS2);
    }

    // ---- block reduction (4 waves of 64) ----
    #pragma unroll
    for (int off = 32; off > 0; off >>= 1)
        s += __shfl_down(s, off, 64);
    if ((tid & 63) == 0) wsum[tid >> 6] = s;
    __syncthreads();

    // ---- fused grid reduction: relaxed fixed-point atomics ----
    if (tid == 0) {
        const float bsum = (wsum[0] + wsum[1]) + (wsum[2] + wsum[3]);
        const unsigned long long q =
            (unsigned long long)llrint((double)bsum * FXSCALE_D);
        const unsigned long long prev =
            __hip_atomic_fetch_add(total_fx, q,
                                   __ATOMIC_RELAXED, __HIP_MEMORY_SCOPE_AGENT);
        // Data dependency on `prev` forces s_waitcnt vmcnt(0) here: the
        // fx RMW has completed at the coherence point before the counter
        // bump below issues. Wave-local wait; no cache invalidation.
        asm volatile("" :: "v"((unsigned int)prev) : "memory");
        const unsigned int old =
            __hip_atomic_fetch_add(counter, 1u,
                                   __ATOMIC_RELAXED, __HIP_MEMORY_SCOPE_AGENT);
        if (old == GRID - 1) {            // last block: finalize
            const unsigned long long t =
                __hip_atomic_load(total_fx,
                                  __ATOMIC_RELAXED, __HIP_MEMORY_SCOPE_AGENT);
            out[0] = (float)((double)t /
                             (FXSCALE_D * (double)(NB * CH * HH * WW)));
        }
    }
}

extern "C" void kernel_launch(void* const* d_in, const int* in_sizes, int n_in,
                              void* d_out, int out_size, void* d_ws, size_t ws_size,
                              hipStream_t stream) {
    const float* image1  = (const float*)d_in[0];
    const float* image2  = (const float*)d_in[1];
    const float* filters = (const float*)d_in[2];
    float* out = (float*)d_out;

    unsigned long long* total_fx = (unsigned long long*)d_ws;        // 8 B
    unsigned int*       counter  = (unsigned int*)((char*)d_ws + 8); // 4 B

    // zero accumulator + counter each call (graph-capture-safe)
    hipMemsetAsync(d_ws, 0, 16, stream);

    recon_charbonnier_fused<<<GRID, 256, 0, stream>>>(image1, image2, filters,
                                                      total_fx, counter, out);
}

// Round 8
// 30.754 us; speedup vs baseline: 1.2188x; 1.2188x over previous
//
#include <hip/hip_runtime.h>
#include <math.h>

// Problem constants (match reference setup_inputs)
#define KF   11
#define PAD  5          // KF/2
#define NB   4
#define CH   3
#define HH   256
#define WW   256
#define HWSZ (HH * WW)
#define EPS2 (1e-3f * 1e-3f)

#define RPB   2                    // output rows per block
#define SROWS (RPB + KF - 1)       // 12 staged rows per channel
#define LW    272                  // LDS row width (floats)
#define LPAD  8                    // left pad: quad-aligned windows cover the -5 halo
#define LW4   (LW / 4)             // 68 float4 per LDS row
#define STOT  (CH * SROWS * LW4)   // 2448 float4 staging elements

// Round-6 structure (best: 30.74 us) + explicit 2-deep dh software pipeline:
//   - named fvA/fvB filter-load buffers (static indexing -> stays in VGPRs;
//     round-4's array version was folded away, VGPR=68 proved it)
//   - dh0's 11 loads issued BEFORE the LDS staging loop (overlap ~900cy
//     cold-load latency with staging + barrier)
//   - image2 loads hoisted ahead of the tap loop
__global__ __launch_bounds__(256, 2) void recon_charbonnier_kernel(
    const float* __restrict__ image1,
    const float* __restrict__ image2,
    const float* __restrict__ filters,
    float* __restrict__ block_sums)
{
    __shared__ float limg[CH][SROWS][LW];   // 39,168 B
    __shared__ float part[CH][RPB][WW];     //  6,144 B
    __shared__ float wsum[4];

    const int tid  = threadIdx.x;
    const int p    = tid & 63;
    const int r    = (tid >> 6) & 1;
    const int half = tid >> 7;
    const int b    = blockIdx.x;
    const int n    = b >> 7;            // 4 batches
    const int h0   = (b & 127) << 1;    // 128 bands of 2 rows

    const float* __restrict__ img1n = image1 + (size_t)n * CH * HWSZ;

    const int w0 = p << 2;
    const float* __restrict__ fp = filters + (size_t)n * (KF * KF) * HWSZ
                                           + (size_t)(h0 + r) * WW + w0;
    const int dhBeg = half ? 6 : 0;       // wave-uniform
    const int dhCnt = half ? 5 : 6;

    float4 fvA[KF], fvB[KF];

    // ---- issue dh0's filter loads FIRST (latency hides under staging) ----
    #pragma unroll
    for (int dw = 0; dw < KF; ++dw)
        fvA[dw] = *(const float4*)(fp + (size_t)(dhBeg * KF + dw) * HWSZ);

    // ---- stage image1 band (rows h0-5 .. h0+6, 3 ch) into LDS, zero halo ----
    for (int idx = tid; idx < STOT; idx += 256) {
        const int row = idx / LW4;            // ch*SROWS + rr
        const int c4  = idx - row * LW4;      // 0..67
        const int ch  = row / SROWS;
        const int rr  = row - ch * SROWS;
        const int grow = h0 + rr - PAD;
        const int gcol = (c4 << 2) - LPAD;
        float4 v = make_float4(0.f, 0.f, 0.f, 0.f);
        if ((unsigned)grow < (unsigned)HH && (unsigned)gcol <= (unsigned)(WW - 4))
            v = *(const float4*)(img1n + (size_t)ch * HWSZ
                                       + (size_t)grow * WW + gcol);
        *(float4*)&limg[ch][rr][c4 << 2] = v;
    }

    // hoist image2 loads (consumed after the tap loop)
    const float* __restrict__ img2p = image2 + (size_t)n * CH * HWSZ
                                             + (size_t)(h0 + r) * WW + w0;
    float4 t2[CH];
    if (!half) {
        #pragma unroll
        for (int ch = 0; ch < CH; ++ch)
            t2[ch] = *(const float4*)(img2p + (size_t)ch * HWSZ);
    }

    __syncthreads();

    float acc[CH][4] = {};

    // one dh-step: consume filter regs FV for tap-row dh, quad-aligned windows
    #define COMPUTE_DH(FV, dh)                                                 \
        do {                                                                   \
            _Pragma("unroll")                                                  \
            for (int ch = 0; ch < CH; ++ch) {                                  \
                float win[20];                                                 \
                _Pragma("unroll")                                              \
                for (int k = 0; k < 5; ++k) {                                  \
                    const float4 q =                                           \
                        *(const float4*)&limg[ch][r + (dh)][w0 + (k << 2)];    \
                    win[4 * k + 0] = q.x;                                      \
                    win[4 * k + 1] = q.y;                                      \
                    win[4 * k + 2] = q.z;                                      \
                    win[4 * k + 3] = q.w;                                      \
                }                                                              \
                _Pragma("unroll")                                              \
                for (int dw = 0; dw < KF; ++dw) {                              \
                    acc[ch][0] = fmaf(FV[dw].x, win[dw + 3], acc[ch][0]);      \
                    acc[ch][1] = fmaf(FV[dw].y, win[dw + 4], acc[ch][1]);      \
                    acc[ch][2] = fmaf(FV[dw].z, win[dw + 5], acc[ch][2]);      \
                    acc[ch][3] = fmaf(FV[dw].w, win[dw + 6], acc[ch][3]);      \
                }                                                              \
            }                                                                  \
        } while (0)

    #define LOAD_DH(FV, dh)                                                    \
        do {                                                                   \
            _Pragma("unroll")                                                  \
            for (int dw = 0; dw < KF; ++dw)                                    \
                FV[dw] = *(const float4*)(fp + (size_t)((dh) * KF + dw) * HWSZ); \
        } while (0)

    // 2-deep software pipeline over this thread's dh range
    for (int i = 0; i < dhCnt; i += 2) {
        const int dh = dhBeg + i;
        if (i + 1 < dhCnt) LOAD_DH(fvB, dh + 1);   // prefetch odd row
        COMPUTE_DH(fvA, dh);
        if (i + 2 < dhCnt) LOAD_DH(fvA, dh + 2);   // prefetch next even row
        if (i + 1 < dhCnt) COMPUTE_DH(fvB, dh + 1);
    }

    #undef COMPUTE_DH
    #undef LOAD_DH

    // ---- combine tap halves via LDS ----
    if (half) {
        #pragma unroll
        for (int ch = 0; ch < CH; ++ch)
            *(float4*)&part[ch][r][w0] =
                make_float4(acc[ch][0], acc[ch][1], acc[ch][2], acc[ch][3]);
    }
    __syncthreads();

    float s = 0.f;
    if (!half) {
        #pragma unroll
        for (int ch = 0; ch < CH; ++ch) {
            const float4 pr = *(const float4*)&part[ch][r][w0];
            const float d0 = acc[ch][0] + pr.x - t2[ch].x;
            const float d1 = acc[ch][1] + pr.y - t2[ch].y;
            const float d2 = acc[ch][2] + pr.z - t2[ch].z;
            const float d3 = acc[ch][3] + pr.w - t2[ch].w;
            s += sqrtf(d0 * d0 + EPS2) + sqrtf(d1 * d1 + EPS2)
               + sqrtf(d2 * d2 + EPS2) + sqrtf(d3 * d3 + EPS2);
        }
    }

    // ---- block reduction (4 waves of 64; half1 waves contribute 0) ----
    #pragma unroll
    for (int off = 32; off > 0; off >>= 1)
        s += __shfl_down(s, off, 64);
    if ((tid & 63) == 0) wsum[tid >> 6] = s;
    __syncthreads();
    if (tid == 0)
        block_sums[blockIdx.x] = (wsum[0] + wsum[1]) + (wsum[2] + wsum[3]);
}

// Kernel 2: reduce the 512 per-block sums into the scalar mean.
__global__ __launch_bounds__(256) void final_reduce_kernel(
    const float* __restrict__ block_sums,
    float* __restrict__ out)
{
    float s = block_sums[threadIdx.x] + block_sums[threadIdx.x + 256];

    #pragma unroll
    for (int off = 32; off > 0; off >>= 1)
        s += __shfl_down(s, off, 64);

    __shared__ float wsum[4];
    if ((threadIdx.x & 63) == 0) wsum[threadIdx.x >> 6] = s;
    __syncthreads();
    if (threadIdx.x == 0) {
        const float inv_count = 1.0f / (float)(NB * CH * HH * WW);
        out[0] = ((wsum[0] + wsum[1]) + (wsum[2] + wsum[3])) * inv_count;
    }
}

extern "C" void kernel_launch(void* const* d_in, const int* in_sizes, int n_in,
                              void* d_out, int out_size, void* d_ws, size_t ws_size,
                              hipStream_t stream) {
    const float* image1  = (const float*)d_in[0];
    const float* image2  = (const float*)d_in[1];
    const float* filters = (const float*)d_in[2];
    float* out = (float*)d_out;
    float* block_sums = (float*)d_ws;   // 512 floats

    const int grid = NB * (HH / RPB);   // 512 blocks, one per (n, 2-row band)

    recon_charbonnier_kernel<<<grid, 256, 0, stream>>>(image1, image2, filters,
                                                       block_sums);
    final_reduce_kernel<<<1, 256, 0, stream>>>(block_sums, out);
}